// Round 1
// baseline (886.156 us; speedup 1.0000x reference)
//
#include <hip/hip_runtime.h>

// Problem constants (B=8, S=2048, D=1024, H=4096, E=8, CAP_FACTOR=1.5)
#define NTOK 16384
#define DDIM 1024
#define EEXP 8
#define HDIM 4096
#define CAP  3072               // int(1.5 * 16384 / 8)
#define ECAP (EEXP*CAP)         // 24576
#define RT_PER_E (CAP/128)      // 24 row-tiles per expert

// Workspace layout (bytes)
#define OFF_GATE 0u                          // float[NTOK]
#define OFF_GIDX 65536u                      // int[NTOK]
#define OFF_SLOT 131072u                     // int[NTOK]
#define OFF_TOS  196608u                     // int[ECAP]
#define OFF_CNT  294912u                     // int[8]
#define OFF_PIMP 294976u                     // float[4096*8]
#define OFF_XBF  1048576u                    // ushort[NTOK*DDIM]       (32 MB)
#define OFF_W1T  34603008u                   // ushort[E*HDIM*DDIM]     (64 MB) [e][n][k]
#define OFF_W2T  101711872u                  // ushort[E*DDIM*HDIM]     (64 MB) [e][n][k]
#define OFF_HB   168820736u                  // ushort[ECAP*HDIM]       (192 MB)
#define WS_NEED  370147328u

typedef float f32x4  __attribute__((ext_vector_type(4)));
typedef short bf16x8 __attribute__((ext_vector_type(8)));
typedef unsigned short u16x8 __attribute__((ext_vector_type(8)));

__device__ __forceinline__ unsigned short f2bf(float f){
  unsigned int u = __float_as_uint(f);
  unsigned int r = (u + 0x7fffu + ((u >> 16) & 1u)) >> 16;   // RNE
  return (unsigned short)r;
}
__device__ __forceinline__ float siluf(float v){ return v/(1.0f+__expf(-v)); }

// async global->LDS, 16B per lane; LDS dst must be wave-uniform base (+lane*16 implicit)
__device__ __forceinline__ void gl16(const void* g, void* l){
  __builtin_amdgcn_global_load_lds((const __attribute__((address_space(1))) unsigned int*)g,
                                   (__attribute__((address_space(3))) unsigned int*)l,
                                   16, 0, 0);
}

// ---------------------------------------------------------------------------
// Router: one wave per token. Also emits x in bf16 (fused conversion).
// ---------------------------------------------------------------------------
__global__ __launch_bounds__(256) void router_kernel(
    const float* __restrict__ x, const float* __restrict__ Wr,
    const float* __restrict__ br, float* __restrict__ gate_value,
    int* __restrict__ gate_idx, float* __restrict__ partial_imp,
    unsigned short* __restrict__ xbf)
{
  __shared__ float pbuf[4][8];
  const int wave = threadIdx.x >> 6;
  const int lane = threadIdx.x & 63;
  const int n = blockIdx.x*4 + wave;
  float acc[8];
#pragma unroll
  for (int e=0;e<8;e++) acc[e]=0.0f;
  const float* xr = x + (size_t)n*DDIM;
  unsigned short* xbr = xbf + (size_t)n*DDIM;
#pragma unroll
  for (int k=0;k<16;k++){
    const int d = k*64 + lane;
    const float xv = xr[d];
    xbr[d] = f2bf(xv);
    const float4 w0 = ((const float4*)(Wr + (size_t)d*8))[0];
    const float4 w1 = ((const float4*)(Wr + (size_t)d*8))[1];
    acc[0] += xv*w0.x; acc[1] += xv*w0.y; acc[2] += xv*w0.z; acc[3] += xv*w0.w;
    acc[4] += xv*w1.x; acc[5] += xv*w1.y; acc[6] += xv*w1.z; acc[7] += xv*w1.w;
  }
#pragma unroll
  for (int e=0;e<8;e++){
    acc[e] += __shfl_xor(acc[e], 32, 64);
    acc[e] += __shfl_xor(acc[e], 16, 64);
    acc[e] += __shfl_xor(acc[e],  8, 64);
    acc[e] += __shfl_xor(acc[e],  4, 64);
    acc[e] += __shfl_xor(acc[e],  2, 64);
    acc[e] += __shfl_xor(acc[e],  1, 64);
  }
  if (lane==0){
    float lg[8];
    float mx = -3.4e38f;
    int bi = 0;
#pragma unroll
    for (int e=0;e<8;e++) lg[e] = acc[e] + br[e];
#pragma unroll
    for (int e=0;e<8;e++){ if (lg[e] > mx){ mx = lg[e]; bi = e; } }
    float s = 0.f;
#pragma unroll
    for (int e=0;e<8;e++){ lg[e] = __expf(lg[e]-mx); s += lg[e]; }
    const float inv = 1.0f/s;
    gate_value[n] = inv;
    gate_idx[n] = bi;
#pragma unroll
    for (int e=0;e<8;e++) pbuf[wave][e] = lg[e]*inv;
  }
  __syncthreads();
  if (threadIdx.x < 8){
    partial_imp[(size_t)blockIdx.x*8 + threadIdx.x] =
      pbuf[0][threadIdx.x]+pbuf[1][threadIdx.x]+pbuf[2][threadIdx.x]+pbuf[3][threadIdx.x];
  }
}

// ---------------------------------------------------------------------------
// Scan: FIFO positions per expert (single block) + aux losses.
// ---------------------------------------------------------------------------
__global__ __launch_bounds__(256) void scan_kernel(
    const int* __restrict__ gate_idx, const float* __restrict__ partial_imp,
    int* __restrict__ slot_or_neg, int* __restrict__ tok_of_slot,
    int* __restrict__ cnt, float* __restrict__ out_losses)
{
  __shared__ int hist[256][8];
  __shared__ float impbuf[32][8];
  const int t = threadIdx.x;
  int h[8];
#pragma unroll
  for (int e=0;e<8;e++) h[e]=0;
  const int base = t*64;
  for (int i=0;i<64;i++) h[gate_idx[base+i]]++;
#pragma unroll
  for (int e=0;e<8;e++) hist[t][e]=h[e];
  {
    const int e = t & 7, c = t >> 3;
    float s = 0.f;
    for (int r=c; r<4096; r+=32) s += partial_imp[(size_t)r*8+e];
    impbuf[c][e] = s;
  }
  __syncthreads();
  if (t < 8){
    int run = 0;
    for (int i=0;i<256;i++){ int v = hist[i][t]; hist[i][t] = run; run += v; }
    cnt[t] = run < CAP ? run : CAP;
  }
  __syncthreads();
#pragma unroll
  for (int e=0;e<8;e++) h[e]=hist[t][e];
  for (int i=0;i<64;i++){
    const int n = base+i;
    const int e = gate_idx[n];
    const int p = h[e]++;
    if (p < CAP){ const int s = e*CAP+p; slot_or_neg[n]=s; tok_of_slot[s]=n; }
    else slot_or_neg[n] = -1;
  }
  if (t==0){
    float imp[8]; float m = 0.f;
    for (int e=0;e<8;e++){ float s=0.f; for (int c=0;c<32;c++) s+=impbuf[c][e]; imp[e]=s; m+=s; }
    m *= 0.125f;
    float var = 0.f;
    for (int e=0;e<8;e++){ const float d=imp[e]-m; var += d*d; }
    var *= 0.125f;
    out_losses[0] = 1.0f;
    out_losses[1] = var/(m*m);
  }
}

// ---------------------------------------------------------------------------
// Weight transpose + fp32->bf16: W [E][K][N] -> Wt [E][N][K] (k-contiguous rows,
// as required by the MFMA B-operand). grid (N/32, K/32, E), 256 threads.
// Store side widened to 16B/lane (ushort8), 128 active store lanes.
// ---------------------------------------------------------------------------
__global__ __launch_bounds__(256) void cvt_w_t(
    const float* __restrict__ W, unsigned short* __restrict__ Wt, int K, int N)
{
  __shared__ float t[32][33];
  const int e = blockIdx.z;
  const int n0 = blockIdx.x*32, k0 = blockIdx.y*32;
  const int r = threadIdx.x>>3, c4 = (threadIdx.x&7)*4;
  const float4 v = *(const float4*)(W + ((size_t)e*K + k0 + r)*N + n0 + c4);
  t[r][c4+0]=v.x; t[r][c4+1]=v.y; t[r][c4+2]=v.z; t[r][c4+3]=v.w;
  __syncthreads();
  if (threadIdx.x < 128){
    const int r2 = threadIdx.x>>2;        // output row in n-tile: 0..31
    const int c8 = (threadIdx.x&3)*8;     // k offset: 0,8,16,24
    u16x8 o;
#pragma unroll
    for (int j=0;j<8;j++) o[j] = f2bf(t[c8+j][r2]);
    *(u16x8*)(Wt + ((size_t)e*N + n0 + r2)*K + k0 + c8) = o;
  }
}

// ---------------------------------------------------------------------------
// MFMA grouped FFN GEMM: 128x128 tile, BK=32 bf16, 4 waves, each wave 64x64
// via 4x4 grid of v_mfma_f32_16x16x32_bf16.
// T3 "minimum 2-phase": double-buffered LDS (2 x 16KB). Per K-step: issue the
// 4 global_load_lds for tile k+1 into buf^1, then ds_read+MFMA tile k from
// buf, then ONE __syncthreads (its implicit vmcnt(0) drains our own loads;
// since every wave drains its own before the barrier, the full tile is
// resident after it — no inline-asm waitcnt needed, no reorder race).
// LDS chunk swizzle unchanged: chunk(r,kg) at r*64 + (kg ^ ((r>>1)&3))*16.
// PHASE 1: hbf = bf16(silu(Xg @ W1^T' + b1));  PHASE 2: out[tok] = (h @ W2^T' + b2)*gate
// ---------------------------------------------------------------------------
template<int PHASE>
__global__ __launch_bounds__(256) void ffn_mfma(
    const unsigned short* __restrict__ A,   // PHASE1: xbf [NTOK][1024]; PHASE2: hbf [ECAP][4096]
    const unsigned short* __restrict__ Bt,  // [E][NN][K] k-contiguous
    const float* __restrict__ bias,         // [E][NN]
    const int* __restrict__ tok_of_slot,
    const int* __restrict__ cnt,
    const float* __restrict__ gate_value,
    void* __restrict__ Out)
{
  constexpr int K  = (PHASE==1)? DDIM : HDIM;
  constexpr int NN = (PHASE==1)? HDIM : DDIM;
  const int rowtile = blockIdx.y;
  const int coltile = blockIdx.x;
  const int e  = rowtile / RT_PER_E;
  const int r0 = (rowtile - e*RT_PER_E)*128;
  const int ce = cnt[e];
  if (r0 >= ce) return;                     // block-uniform early exit

  __shared__ alignas(16) char smem[32768];  // 2 buffers x (A 8KB + B 8KB)
  char* As  = smem;                         // + bufoff
  char* Bsm = smem + 8192;                  // + bufoff

  const int tid  = threadIdx.x;
  const int l    = tid & 63;
  const int wv   = __builtin_amdgcn_readfirstlane(tid >> 6);

  // ---- staging addresses (2 A chunks + 2 B chunks per lane per K-step)
  const int sub = l >> 2;                   // 0..15
  const int c   = l & 3;
  const int gr0 = wv*16 + sub;              // tile rows 0..63
  const int gr1 = 64 + gr0;                 // tile rows 64..127
  const int kg0 = c ^ ((gr0>>1)&3);
  const int kg1 = c ^ ((gr1>>1)&3);

  const unsigned short *agp0, *agp1;
  if (PHASE==1){
    const int t0 = (r0 + gr0 < ce) ? tok_of_slot[rowtile*128 + gr0] : 0;
    const int t1 = (r0 + gr1 < ce) ? tok_of_slot[rowtile*128 + gr1] : 0;
    agp0 = A + (size_t)t0*K + kg0*8;
    agp1 = A + (size_t)t1*K + kg1*8;
  } else {
    agp0 = A + (size_t)(rowtile*128 + gr0)*K + kg0*8;
    agp1 = A + (size_t)(rowtile*128 + gr1)*K + kg1*8;
  }
  const unsigned short* bgp0 = Bt + ((size_t)e*NN + coltile*128 + gr0)*K + kg0*8;
  const unsigned short* bgp1 = Bt + ((size_t)e*NN + coltile*128 + gr1)*K + kg1*8;

  char* a_dst0 = As  + wv*1024;  char* a_dst1 = As  + 4096 + wv*1024;
  char* b_dst0 = Bsm + wv*1024;  char* b_dst1 = Bsm + 4096 + wv*1024;

  // ---- fragment read offsets
  const int wrow = (wv & 1)*64, wcol = (wv >> 1)*64;
  const int lm  = l & 15;
  const int kgf = l >> 4;                   // 0..3
  int aoff[4], bofs[4];
#pragma unroll
  for (int i=0;i<4;i++){
    const int ra = wrow + i*16 + lm;
    aoff[i] = ra*64 + ((kgf ^ ((ra>>1)&3))*16);
    const int rb = wcol + i*16 + lm;
    bofs[i] = rb*64 + ((kgf ^ ((rb>>1)&3))*16);
  }

  f32x4 acc[4][4];
#pragma unroll
  for (int i=0;i<4;i++)
#pragma unroll
    for (int j=0;j<4;j++) acc[i][j] = (f32x4){0.f,0.f,0.f,0.f};

  // ---- prologue: stage tile k=0 into buffer 0
  gl16(agp0, a_dst0);
  gl16(agp1, a_dst1);
  gl16(bgp0, b_dst0);
  gl16(bgp1, b_dst1);
  __syncthreads();                          // drains vmcnt(0): tile 0 resident

  int bufoff = 0;
#pragma unroll 2
  for (int k0 = 32; k0 < K; k0 += 32){
    const int nb = bufoff ^ 16384;
    // issue next tile's loads first (latency hides under ds_read + MFMA)
    gl16(agp0 + k0, a_dst0 + nb);
    gl16(agp1 + k0, a_dst1 + nb);
    gl16(bgp0 + k0, b_dst0 + nb);
    gl16(bgp1 + k0, b_dst1 + nb);
    // compute current tile
    bf16x8 af[4], bfr[4];
#pragma unroll
    for (int i=0;i<4;i++) af[i]  = *(const bf16x8*)(As  + bufoff + aoff[i]);
#pragma unroll
    for (int i=0;i<4;i++) bfr[i] = *(const bf16x8*)(Bsm + bufoff + bofs[i]);
#pragma unroll
    for (int mi=0;mi<4;mi++)
#pragma unroll
      for (int ni=0;ni<4;ni++)
        acc[mi][ni] = __builtin_amdgcn_mfma_f32_16x16x32_bf16(af[mi], bfr[ni], acc[mi][ni], 0, 0, 0);
    __syncthreads();                        // drains own vmcnt(0) -> next tile resident; protects buffer reuse
    bufoff = nb;
  }
  { // epilogue K-step: compute the last staged buffer
    bf16x8 af[4], bfr[4];
#pragma unroll
    for (int i=0;i<4;i++) af[i]  = *(const bf16x8*)(As  + bufoff + aoff[i]);
#pragma unroll
    for (int i=0;i<4;i++) bfr[i] = *(const bf16x8*)(Bsm + bufoff + bofs[i]);
#pragma unroll
    for (int mi=0;mi<4;mi++)
#pragma unroll
      for (int ni=0;ni<4;ni++)
        acc[mi][ni] = __builtin_amdgcn_mfma_f32_16x16x32_bf16(af[mi], bfr[ni], acc[mi][ni], 0, 0, 0);
  }

  // ---- epilogue. C/D layout: col = lane&15, row = (lane>>4)*4 + reg
  const float* bp = bias + (size_t)e*NN + coltile*128 + wcol;
  float bv[4];
#pragma unroll
  for (int ni=0;ni<4;ni++) bv[ni] = bp[ni*16 + lm];

  if (PHASE==1){
    unsigned short* hb = (unsigned short*)Out;
#pragma unroll
    for (int mi=0;mi<4;mi++){
#pragma unroll
      for (int r=0;r<4;r++){
        const int row = wrow + mi*16 + kgf*4 + r;
        unsigned short* hr = hb + (size_t)(rowtile*128 + row)*NN + coltile*128 + wcol;
#pragma unroll
        for (int ni=0;ni<4;ni++){
          const float v = acc[mi][ni][r] + bv[ni];
          hr[ni*16 + lm] = f2bf(siluf(v));
        }
      }
    }
  } else {
    float* op = (float*)Out;
#pragma unroll
    for (int mi=0;mi<4;mi++){
#pragma unroll
      for (int r=0;r<4;r++){
        const int row = wrow + mi*16 + kgf*4 + r;
        if (r0 + row < ce){
          const int tok = tok_of_slot[rowtile*128 + row];
          const float g = gate_value[tok];
          float* orow = op + (size_t)tok*NN + coltile*128 + wcol;
#pragma unroll
          for (int ni=0;ni<4;ni++)
            orow[ni*16 + lm] = (acc[mi][ni][r] + bv[ni])*g;
        }
      }
    }
  }
}

// ---------------------------------------------------------------------------
// Dropped tokens pass through: out[n] = x[n] * gate[n]. One wave per token.
// ---------------------------------------------------------------------------
__global__ __launch_bounds__(256) void passthrough_kernel(
    const float* __restrict__ x, const int* __restrict__ slot_or_neg,
    const float* __restrict__ gate_value, float* __restrict__ out)
{
  const int wave = threadIdx.x >> 6;
  const int lane = threadIdx.x & 63;
  const int n = blockIdx.x*4 + wave;
  if (slot_or_neg[n] >= 0) return;
  const float g = gate_value[n];
#pragma unroll
  for (int k=0;k<4;k++){
    const int d = (k*64 + lane)*4;
    float4 v = *(const float4*)(x + (size_t)n*DDIM + d);
    v.x*=g; v.y*=g; v.z*=g; v.w*=g;
    *(float4*)(out + (size_t)n*DDIM + d) = v;
  }
}

extern "C" void kernel_launch(void* const* d_in, const int* in_sizes, int n_in,
                              void* d_out, int out_size, void* d_ws, size_t ws_size,
                              hipStream_t stream)
{
  const float* x  = (const float*)d_in[0];
  const float* Wr = (const float*)d_in[1];
  const float* br = (const float*)d_in[2];
  const float* W1 = (const float*)d_in[3];
  const float* b1 = (const float*)d_in[4];
  const float* W2 = (const float*)d_in[5];
  const float* b2 = (const float*)d_in[6];
  float* out = (float*)d_out;

  char* ws = (char*)d_ws;
  float*          gate_value  = (float*)(ws + OFF_GATE);
  int*            gate_idx    = (int*)  (ws + OFF_GIDX);
  int*            slot_or_neg = (int*)  (ws + OFF_SLOT);
  int*            tok_of_slot = (int*)  (ws + OFF_TOS);
  int*            cnt         = (int*)  (ws + OFF_CNT);
  float*          partial_imp = (float*)(ws + OFF_PIMP);
  unsigned short* xbf         = (unsigned short*)(ws + OFF_XBF);
  unsigned short* W1t         = (unsigned short*)(ws + OFF_W1T);
  unsigned short* W2t         = (unsigned short*)(ws + OFF_W2T);
  unsigned short* hbf         = (unsigned short*)(ws + OFF_HB);

  // weight transpose+convert (independent of router/scan)
  cvt_w_t<<<dim3(HDIM/32, DDIM/32, EEXP), 256, 0, stream>>>(W1, W1t, DDIM, HDIM);
  cvt_w_t<<<dim3(DDIM/32, HDIM/32, EEXP), 256, 0, stream>>>(W2, W2t, HDIM, DDIM);

  router_kernel<<<NTOK/4, 256, 0, stream>>>(x, Wr, br, gate_value, gate_idx,
                                            partial_imp, xbf);
  scan_kernel<<<1, 256, 0, stream>>>(gate_idx, partial_imp, slot_or_neg, tok_of_slot,
                                     cnt, out + (size_t)NTOK*DDIM);

  ffn_mfma<1><<<dim3(HDIM/128, ECAP/128), 256, 0, stream>>>(
      xbf, W1t, b1, tok_of_slot, cnt, gate_value, (void*)hbf);
  ffn_mfma<2><<<dim3(DDIM/128, ECAP/128), 256, 0, stream>>>(
      hbf, W2t, b2, tok_of_slot, cnt, gate_value, (void*)out);

  passthrough_kernel<<<NTOK/4, 256, 0, stream>>>(x, slot_or_neg, gate_value, out);
}

// Round 2
// 877.144 us; speedup vs baseline: 1.0103x; 1.0103x over previous
//
#include <hip/hip_runtime.h>

// Problem constants (B=8, S=2048, D=1024, H=4096, E=8, CAP_FACTOR=1.5)
#define NTOK 16384
#define DDIM 1024
#define EEXP 8
#define HDIM 4096
#define CAP  3072               // int(1.5 * 16384 / 8)
#define ECAP (EEXP*CAP)         // 24576
#define RT_PER_E (CAP/128)      // 24 row-tiles per expert

// Workspace layout (bytes)
#define OFF_GATE 0u                          // float[NTOK]
#define OFF_GIDX 65536u                      // int[NTOK]
#define OFF_SLOT 131072u                     // int[NTOK]
#define OFF_TOS  196608u                     // int[ECAP]
#define OFF_CNT  294912u                     // int[8]
#define OFF_PIMP 294976u                     // float[4096*8]
#define OFF_XBF  1048576u                    // ushort[NTOK*DDIM]       (32 MB)
#define OFF_W1T  34603008u                   // ushort[E*HDIM*DDIM]     (64 MB) [e][n][k]
#define OFF_W2T  101711872u                  // ushort[E*DDIM*HDIM]     (64 MB) [e][n][k]
#define OFF_HB   168820736u                  // ushort[ECAP*HDIM]       (192 MB)
#define WS_NEED  370147328u

typedef float f32x4  __attribute__((ext_vector_type(4)));
typedef short bf16x8 __attribute__((ext_vector_type(8)));
typedef unsigned short u16x8 __attribute__((ext_vector_type(8)));

__device__ __forceinline__ unsigned short f2bf(float f){
  unsigned int u = __float_as_uint(f);
  unsigned int r = (u + 0x7fffu + ((u >> 16) & 1u)) >> 16;   // RNE
  return (unsigned short)r;
}
__device__ __forceinline__ float siluf(float v){ return v/(1.0f+__expf(-v)); }

// async global->LDS, 16B per lane; LDS dst must be wave-uniform base (+lane*16 implicit)
__device__ __forceinline__ void gl16(const void* g, void* l){
  __builtin_amdgcn_global_load_lds((const __attribute__((address_space(1))) unsigned int*)g,
                                   (__attribute__((address_space(3))) unsigned int*)l,
                                   16, 0, 0);
}

// ---------------------------------------------------------------------------
// Router: one wave per token. Also emits x in bf16 (fused conversion).
// ---------------------------------------------------------------------------
__global__ __launch_bounds__(256) void router_kernel(
    const float* __restrict__ x, const float* __restrict__ Wr,
    const float* __restrict__ br, float* __restrict__ gate_value,
    int* __restrict__ gate_idx, float* __restrict__ partial_imp,
    unsigned short* __restrict__ xbf)
{
  __shared__ float pbuf[4][8];
  const int wave = threadIdx.x >> 6;
  const int lane = threadIdx.x & 63;
  const int n = blockIdx.x*4 + wave;
  float acc[8];
#pragma unroll
  for (int e=0;e<8;e++) acc[e]=0.0f;
  const float* xr = x + (size_t)n*DDIM;
  unsigned short* xbr = xbf + (size_t)n*DDIM;
#pragma unroll
  for (int k=0;k<16;k++){
    const int d = k*64 + lane;
    const float xv = xr[d];
    xbr[d] = f2bf(xv);
    const float4 w0 = ((const float4*)(Wr + (size_t)d*8))[0];
    const float4 w1 = ((const float4*)(Wr + (size_t)d*8))[1];
    acc[0] += xv*w0.x; acc[1] += xv*w0.y; acc[2] += xv*w0.z; acc[3] += xv*w0.w;
    acc[4] += xv*w1.x; acc[5] += xv*w1.y; acc[6] += xv*w1.z; acc[7] += xv*w1.w;
  }
#pragma unroll
  for (int e=0;e<8;e++){
    acc[e] += __shfl_xor(acc[e], 32, 64);
    acc[e] += __shfl_xor(acc[e], 16, 64);
    acc[e] += __shfl_xor(acc[e],  8, 64);
    acc[e] += __shfl_xor(acc[e],  4, 64);
    acc[e] += __shfl_xor(acc[e],  2, 64);
    acc[e] += __shfl_xor(acc[e],  1, 64);
  }
  if (lane==0){
    float lg[8];
    float mx = -3.4e38f;
    int bi = 0;
#pragma unroll
    for (int e=0;e<8;e++) lg[e] = acc[e] + br[e];
#pragma unroll
    for (int e=0;e<8;e++){ if (lg[e] > mx){ mx = lg[e]; bi = e; } }
    float s = 0.f;
#pragma unroll
    for (int e=0;e<8;e++){ lg[e] = __expf(lg[e]-mx); s += lg[e]; }
    const float inv = 1.0f/s;
    gate_value[n] = inv;
    gate_idx[n] = bi;
#pragma unroll
    for (int e=0;e<8;e++) pbuf[wave][e] = lg[e]*inv;
  }
  __syncthreads();
  if (threadIdx.x < 8){
    partial_imp[(size_t)blockIdx.x*8 + threadIdx.x] =
      pbuf[0][threadIdx.x]+pbuf[1][threadIdx.x]+pbuf[2][threadIdx.x]+pbuf[3][threadIdx.x];
  }
}

// ---------------------------------------------------------------------------
// Scan: FIFO positions per expert (single block) + aux losses.
// ---------------------------------------------------------------------------
__global__ __launch_bounds__(256) void scan_kernel(
    const int* __restrict__ gate_idx, const float* __restrict__ partial_imp,
    int* __restrict__ slot_or_neg, int* __restrict__ tok_of_slot,
    int* __restrict__ cnt, float* __restrict__ out_losses)
{
  __shared__ int hist[256][8];
  __shared__ float impbuf[32][8];
  const int t = threadIdx.x;
  int h[8];
#pragma unroll
  for (int e=0;e<8;e++) h[e]=0;
  const int base = t*64;
  for (int i=0;i<64;i++) h[gate_idx[base+i]]++;
#pragma unroll
  for (int e=0;e<8;e++) hist[t][e]=h[e];
  {
    const int e = t & 7, c = t >> 3;
    float s = 0.f;
    for (int r=c; r<4096; r+=32) s += partial_imp[(size_t)r*8+e];
    impbuf[c][e] = s;
  }
  __syncthreads();
  if (t < 8){
    int run = 0;
    for (int i=0;i<256;i++){ int v = hist[i][t]; hist[i][t] = run; run += v; }
    cnt[t] = run < CAP ? run : CAP;
  }
  __syncthreads();
#pragma unroll
  for (int e=0;e<8;e++) h[e]=hist[t][e];
  for (int i=0;i<64;i++){
    const int n = base+i;
    const int e = gate_idx[n];
    const int p = h[e]++;
    if (p < CAP){ const int s = e*CAP+p; slot_or_neg[n]=s; tok_of_slot[s]=n; }
    else slot_or_neg[n] = -1;
  }
  if (t==0){
    float imp[8]; float m = 0.f;
    for (int e=0;e<8;e++){ float s=0.f; for (int c=0;c<32;c++) s+=impbuf[c][e]; imp[e]=s; m+=s; }
    m *= 0.125f;
    float var = 0.f;
    for (int e=0;e<8;e++){ const float d=imp[e]-m; var += d*d; }
    var *= 0.125f;
    out_losses[0] = 1.0f;
    out_losses[1] = var/(m*m);
  }
}

// ---------------------------------------------------------------------------
// Weight transpose + fp32->bf16, both W1 and W2 in one launch.
// W [E][K][N] -> Wt [E][N][K] (k-contiguous rows for the MFMA B-operand).
// 64x64 tiles: 16B/lane loads, 16B/lane stores (128B contiguous per n-row).
// grid (64, 16, 16): z<8 -> W1 (K=1024,N=4096, nt=x, kt=y);
//                    z>=8 -> W2 (K=4096,N=1024, nt=y, kt=x).
// ---------------------------------------------------------------------------
__global__ __launch_bounds__(256) void cvt_w_t(
    const float* __restrict__ W1, const float* __restrict__ W2,
    unsigned short* __restrict__ W1t, unsigned short* __restrict__ W2t)
{
  __shared__ float t[64][65];
  const bool second = blockIdx.z >= 8;
  const int e = second ? (int)blockIdx.z - 8 : (int)blockIdx.z;
  const float* W = second ? W2 : W1;
  unsigned short* Wt = second ? W2t : W1t;
  const int K = second ? HDIM : DDIM;
  const int N = second ? DDIM : HDIM;
  const int nt = second ? (int)blockIdx.y : (int)blockIdx.x;
  const int kt = second ? (int)blockIdx.x : (int)blockIdx.y;
  const int n0 = nt*64, k0 = kt*64;

  const int lr = threadIdx.x >> 4;          // 0..15
  const int lc = (threadIdx.x & 15) * 4;    // 0..60
#pragma unroll
  for (int i=0;i<4;i++){
    const int r = i*16 + lr;
    const float4 v = *(const float4*)(W + ((size_t)e*K + k0 + r)*N + n0 + lc);
    t[r][lc+0]=v.x; t[r][lc+1]=v.y; t[r][lc+2]=v.z; t[r][lc+3]=v.w;
  }
  __syncthreads();
  const int sr = threadIdx.x >> 3;          // 0..31 (n-row within half)
  const int sc = (threadIdx.x & 7) * 8;     // 0..56 (k offset)
#pragma unroll
  for (int i=0;i<2;i++){
    const int r = i*32 + sr;
    u16x8 o;
#pragma unroll
    for (int j=0;j<8;j++) o[j] = f2bf(t[sc+j][r]);
    *(u16x8*)(Wt + ((size_t)e*N + n0 + r)*K + k0 + sc) = o;
  }
}

// ---------------------------------------------------------------------------
// MFMA grouped FFN GEMM (m97 structure): 128x128 tile, BK=32 bf16, 4 waves,
// each wave 64x64 via 4x4 grid of v_mfma_f32_16x16x32_bf16. Single-buffer
// 2-barrier K-loop (round-0 structure; dbuf regressed via L2 thrash).
//
// XCD/L2-aware 1-D grid swizzle (T1 variant): each XCD owns a SLAB of
// coltiles for the whole dispatch (phase1: 4 coltiles = 1MB B working set;
// phase2: 1 coltile), iterating rowtiles with coltile fastest so consecutive
// co-resident blocks on an XCD share the A-tile. B-panels stay hot in the
// 4MB per-XCD L2 across all 192 rowtiles -> B fetched ~once per XCD.
//
// LDS: As/Bs 128 rows x 32 bf16, 16B chunks XOR-swizzled: chunk(r,kg) at
// r*64 + (kg ^ ((r>>1)&3))*16.
// PHASE 1: hbf = bf16(silu(Xg @ W1^T' + b1));  PHASE 2: out[tok] = (h @ W2^T' + b2)*gate
// ---------------------------------------------------------------------------
template<int PHASE>
__global__ __launch_bounds__(256) void ffn_mfma(
    const unsigned short* __restrict__ A,   // PHASE1: xbf [NTOK][1024]; PHASE2: hbf [ECAP][4096]
    const unsigned short* __restrict__ Bt,  // [E][NN][K] k-contiguous
    const float* __restrict__ bias,         // [E][NN]
    const int* __restrict__ tok_of_slot,
    const int* __restrict__ cnt,
    const float* __restrict__ gate_value,
    void* __restrict__ Out)
{
  constexpr int K   = (PHASE==1)? DDIM : HDIM;
  constexpr int NN  = (PHASE==1)? HDIM : DDIM;
  constexpr int NCT = NN/128;               // 32 or 8 coltiles
  constexpr int SLAB = NCT/8;               // coltiles per XCD: 4 or 1

  // bid%8 ~ XCD (round-robin dispatch heuristic; wrong mapping only costs speed)
  const int bid = blockIdx.x;
  const int xcd = bid & 7;
  const int idx = bid >> 3;
  const int rowtile = idx / SLAB;
  const int coltile = xcd*SLAB + (idx % SLAB);

  const int e  = rowtile / RT_PER_E;
  const int r0 = (rowtile - e*RT_PER_E)*128;
  const int ce = cnt[e];
  if (r0 >= ce) return;                     // block-uniform early exit

  __shared__ alignas(16) char smem[16384];
  char* As  = smem;
  char* Bsm = smem + 8192;

  const int tid  = threadIdx.x;
  const int l    = tid & 63;
  const int wv   = __builtin_amdgcn_readfirstlane(tid >> 6);

  // ---- staging addresses (2 A chunks + 2 B chunks per lane per K-step)
  const int sub = l >> 2;                   // 0..15
  const int c   = l & 3;
  const int gr0 = wv*16 + sub;              // tile rows 0..63
  const int gr1 = 64 + gr0;                 // tile rows 64..127
  const int kg0 = c ^ ((gr0>>1)&3);
  const int kg1 = c ^ ((gr1>>1)&3);

  const unsigned short *agp0, *agp1;
  if (PHASE==1){
    const int t0 = (r0 + gr0 < ce) ? tok_of_slot[rowtile*128 + gr0] : 0;
    const int t1 = (r0 + gr1 < ce) ? tok_of_slot[rowtile*128 + gr1] : 0;
    agp0 = A + (size_t)t0*K + kg0*8;
    agp1 = A + (size_t)t1*K + kg1*8;
  } else {
    agp0 = A + (size_t)(rowtile*128 + gr0)*K + kg0*8;
    agp1 = A + (size_t)(rowtile*128 + gr1)*K + kg1*8;
  }
  const unsigned short* bgp0 = Bt + ((size_t)e*NN + coltile*128 + gr0)*K + kg0*8;
  const unsigned short* bgp1 = Bt + ((size_t)e*NN + coltile*128 + gr1)*K + kg1*8;

  char* a_dst0 = As  + wv*1024;  char* a_dst1 = As  + 4096 + wv*1024;
  char* b_dst0 = Bsm + wv*1024;  char* b_dst1 = Bsm + 4096 + wv*1024;

  // ---- fragment read offsets
  const int wrow = (wv & 1)*64, wcol = (wv >> 1)*64;
  const int lm  = l & 15;
  const int kgf = l >> 4;                   // 0..3
  int aoff[4], bofs[4];
#pragma unroll
  for (int i=0;i<4;i++){
    const int ra = wrow + i*16 + lm;
    aoff[i] = ra*64 + ((kgf ^ ((ra>>1)&3))*16);
    const int rb = wcol + i*16 + lm;
    bofs[i] = rb*64 + ((kgf ^ ((rb>>1)&3))*16);
  }

  f32x4 acc[4][4];
#pragma unroll
  for (int i=0;i<4;i++)
#pragma unroll
    for (int j=0;j<4;j++) acc[i][j] = (f32x4){0.f,0.f,0.f,0.f};

  for (int k0 = 0; k0 < K; k0 += 32){
    __syncthreads();                        // prev iter done reading LDS
    gl16(agp0 + k0, a_dst0);
    gl16(agp1 + k0, a_dst1);
    gl16(bgp0 + k0, b_dst0);
    gl16(bgp1 + k0, b_dst1);
    __syncthreads();                        // drains vmcnt -> staging visible
    bf16x8 af[4], bfr[4];
#pragma unroll
    for (int i=0;i<4;i++) af[i]  = *(const bf16x8*)(As  + aoff[i]);
#pragma unroll
    for (int i=0;i<4;i++) bfr[i] = *(const bf16x8*)(Bsm + bofs[i]);
#pragma unroll
    for (int mi=0;mi<4;mi++)
#pragma unroll
      for (int ni=0;ni<4;ni++)
        acc[mi][ni] = __builtin_amdgcn_mfma_f32_16x16x32_bf16(af[mi], bfr[ni], acc[mi][ni], 0, 0, 0);
  }

  // ---- epilogue. C/D layout: col = lane&15, row = (lane>>4)*4 + reg
  const float* bp = bias + (size_t)e*NN + coltile*128 + wcol;
  float bv[4];
#pragma unroll
  for (int ni=0;ni<4;ni++) bv[ni] = bp[ni*16 + lm];

  if (PHASE==1){
    unsigned short* hb = (unsigned short*)Out;
#pragma unroll
    for (int mi=0;mi<4;mi++){
#pragma unroll
      for (int r=0;r<4;r++){
        const int row = wrow + mi*16 + kgf*4 + r;
        unsigned short* hr = hb + (size_t)(rowtile*128 + row)*NN + coltile*128 + wcol;
#pragma unroll
        for (int ni=0;ni<4;ni++){
          const float v = acc[mi][ni][r] + bv[ni];
          hr[ni*16 + lm] = f2bf(siluf(v));
        }
      }
    }
  } else {
    float* op = (float*)Out;
#pragma unroll
    for (int mi=0;mi<4;mi++){
#pragma unroll
      for (int r=0;r<4;r++){
        const int row = wrow + mi*16 + kgf*4 + r;
        if (r0 + row < ce){
          const int tok = tok_of_slot[rowtile*128 + row];
          const float g = gate_value[tok];
          float* orow = op + (size_t)tok*NN + coltile*128 + wcol;
#pragma unroll
          for (int ni=0;ni<4;ni++)
            orow[ni*16 + lm] = (acc[mi][ni][r] + bv[ni])*g;
        }
      }
    }
  }
}

// ---------------------------------------------------------------------------
// Dropped tokens pass through: out[n] = x[n] * gate[n]. One wave per token.
// ---------------------------------------------------------------------------
__global__ __launch_bounds__(256) void passthrough_kernel(
    const float* __restrict__ x, const int* __restrict__ slot_or_neg,
    const float* __restrict__ gate_value, float* __restrict__ out)
{
  const int wave = threadIdx.x >> 6;
  const int lane = threadIdx.x & 63;
  const int n = blockIdx.x*4 + wave;
  if (slot_or_neg[n] >= 0) return;
  const float g = gate_value[n];
#pragma unroll
  for (int k=0;k<4;k++){
    const int d = (k*64 + lane)*4;
    float4 v = *(const float4*)(x + (size_t)n*DDIM + d);
    v.x*=g; v.y*=g; v.z*=g; v.w*=g;
    *(float4*)(out + (size_t)n*DDIM + d) = v;
  }
}

extern "C" void kernel_launch(void* const* d_in, const int* in_sizes, int n_in,
                              void* d_out, int out_size, void* d_ws, size_t ws_size,
                              hipStream_t stream)
{
  const float* x  = (const float*)d_in[0];
  const float* Wr = (const float*)d_in[1];
  const float* br = (const float*)d_in[2];
  const float* W1 = (const float*)d_in[3];
  const float* b1 = (const float*)d_in[4];
  const float* W2 = (const float*)d_in[5];
  const float* b2 = (const float*)d_in[6];
  float* out = (float*)d_out;

  char* ws = (char*)d_ws;
  float*          gate_value  = (float*)(ws + OFF_GATE);
  int*            gate_idx    = (int*)  (ws + OFF_GIDX);
  int*            slot_or_neg = (int*)  (ws + OFF_SLOT);
  int*            tok_of_slot = (int*)  (ws + OFF_TOS);
  int*            cnt         = (int*)  (ws + OFF_CNT);
  float*          partial_imp = (float*)(ws + OFF_PIMP);
  unsigned short* xbf         = (unsigned short*)(ws + OFF_XBF);
  unsigned short* W1t         = (unsigned short*)(ws + OFF_W1T);
  unsigned short* W2t         = (unsigned short*)(ws + OFF_W2T);
  unsigned short* hbf         = (unsigned short*)(ws + OFF_HB);

  // weight transpose+convert (independent of router/scan), single launch
  cvt_w_t<<<dim3(64, 16, 16), 256, 0, stream>>>(W1, W2, W1t, W2t);

  router_kernel<<<NTOK/4, 256, 0, stream>>>(x, Wr, br, gate_value, gate_idx,
                                            partial_imp, xbf);
  scan_kernel<<<1, 256, 0, stream>>>(gate_idx, partial_imp, slot_or_neg, tok_of_slot,
                                     cnt, out + (size_t)NTOK*DDIM);

  ffn_mfma<1><<<dim3((ECAP/128)*(HDIM/128)), 256, 0, stream>>>(
      xbf, W1t, b1, tok_of_slot, cnt, gate_value, (void*)hbf);
  ffn_mfma<2><<<dim3((ECAP/128)*(DDIM/128)), 256, 0, stream>>>(
      hbf, W2t, b2, tok_of_slot, cnt, gate_value, (void*)out);

  passthrough_kernel<<<NTOK/4, 256, 0, stream>>>(x, slot_or_neg, gate_value, out);
}

// Round 3
// 872.484 us; speedup vs baseline: 1.0157x; 1.0053x over previous
//
#include <hip/hip_runtime.h>

// Problem constants (B=8, S=2048, D=1024, H=4096, E=8, CAP_FACTOR=1.5)
#define NTOK 16384
#define DDIM 1024
#define EEXP 8
#define HDIM 4096
#define CAP  3072               // int(1.5 * 16384 / 8)
#define ECAP (EEXP*CAP)         // 24576
#define RT256_PER_E (CAP/256)   // 12 row-tiles (256) per expert

// Workspace layout (bytes)
#define OFF_GATE 0u                          // float[NTOK]
#define OFF_GIDX 65536u                      // int[NTOK]
#define OFF_SLOT 131072u                     // int[NTOK]
#define OFF_TOS  196608u                     // int[ECAP]
#define OFF_CNT  294912u                     // int[8]
#define OFF_PIMP 294976u                     // float[4096*8]
#define OFF_XBF  1048576u                    // ushort[NTOK*DDIM]       (32 MB)
#define OFF_W1T  34603008u                   // ushort[E*HDIM*DDIM]     (64 MB) [e][n][k]
#define OFF_W2T  101711872u                  // ushort[E*DDIM*HDIM]     (64 MB) [e][n][k]
#define OFF_HB   168820736u                  // ushort[ECAP*HDIM]       (192 MB)
#define WS_NEED  370147328u

typedef float f32x4  __attribute__((ext_vector_type(4)));
typedef short bf16x8 __attribute__((ext_vector_type(8)));
typedef unsigned short u16x8 __attribute__((ext_vector_type(8)));

__device__ __forceinline__ unsigned short f2bf(float f){
  unsigned int u = __float_as_uint(f);
  unsigned int r = (u + 0x7fffu + ((u >> 16) & 1u)) >> 16;   // RNE
  return (unsigned short)r;
}
__device__ __forceinline__ float siluf(float v){ return v/(1.0f+__expf(-v)); }

// async global->LDS, 16B per lane; LDS dst must be wave-uniform base (+lane*16 implicit)
__device__ __forceinline__ void gl16(const void* g, void* l){
  __builtin_amdgcn_global_load_lds((const __attribute__((address_space(1))) unsigned int*)g,
                                   (__attribute__((address_space(3))) unsigned int*)l,
                                   16, 0, 0);
}

// ---------------------------------------------------------------------------
// Router: one wave per token. Also emits x in bf16 (fused conversion).
// ---------------------------------------------------------------------------
__global__ __launch_bounds__(256) void router_kernel(
    const float* __restrict__ x, const float* __restrict__ Wr,
    const float* __restrict__ br, float* __restrict__ gate_value,
    int* __restrict__ gate_idx, float* __restrict__ partial_imp,
    unsigned short* __restrict__ xbf)
{
  __shared__ float pbuf[4][8];
  const int wave = threadIdx.x >> 6;
  const int lane = threadIdx.x & 63;
  const int n = blockIdx.x*4 + wave;
  float acc[8];
#pragma unroll
  for (int e=0;e<8;e++) acc[e]=0.0f;
  const float* xr = x + (size_t)n*DDIM;
  unsigned short* xbr = xbf + (size_t)n*DDIM;
#pragma unroll
  for (int k=0;k<16;k++){
    const int d = k*64 + lane;
    const float xv = xr[d];
    xbr[d] = f2bf(xv);
    const float4 w0 = ((const float4*)(Wr + (size_t)d*8))[0];
    const float4 w1 = ((const float4*)(Wr + (size_t)d*8))[1];
    acc[0] += xv*w0.x; acc[1] += xv*w0.y; acc[2] += xv*w0.z; acc[3] += xv*w0.w;
    acc[4] += xv*w1.x; acc[5] += xv*w1.y; acc[6] += xv*w1.z; acc[7] += xv*w1.w;
  }
#pragma unroll
  for (int e=0;e<8;e++){
    acc[e] += __shfl_xor(acc[e], 32, 64);
    acc[e] += __shfl_xor(acc[e], 16, 64);
    acc[e] += __shfl_xor(acc[e],  8, 64);
    acc[e] += __shfl_xor(acc[e],  4, 64);
    acc[e] += __shfl_xor(acc[e],  2, 64);
    acc[e] += __shfl_xor(acc[e],  1, 64);
  }
  if (lane==0){
    float lg[8];
    float mx = -3.4e38f;
    int bi = 0;
#pragma unroll
    for (int e=0;e<8;e++) lg[e] = acc[e] + br[e];
#pragma unroll
    for (int e=0;e<8;e++){ if (lg[e] > mx){ mx = lg[e]; bi = e; } }
    float s = 0.f;
#pragma unroll
    for (int e=0;e<8;e++){ lg[e] = __expf(lg[e]-mx); s += lg[e]; }
    const float inv = 1.0f/s;
    gate_value[n] = inv;
    gate_idx[n] = bi;
#pragma unroll
    for (int e=0;e<8;e++) pbuf[wave][e] = lg[e]*inv;
  }
  __syncthreads();
  if (threadIdx.x < 8){
    partial_imp[(size_t)blockIdx.x*8 + threadIdx.x] =
      pbuf[0][threadIdx.x]+pbuf[1][threadIdx.x]+pbuf[2][threadIdx.x]+pbuf[3][threadIdx.x];
  }
}

// ---------------------------------------------------------------------------
// Scan: FIFO positions per expert (single block) + aux losses.
// ---------------------------------------------------------------------------
__global__ __launch_bounds__(256) void scan_kernel(
    const int* __restrict__ gate_idx, const float* __restrict__ partial_imp,
    int* __restrict__ slot_or_neg, int* __restrict__ tok_of_slot,
    int* __restrict__ cnt, float* __restrict__ out_losses)
{
  __shared__ int hist[256][8];
  __shared__ float impbuf[32][8];
  const int t = threadIdx.x;
  int h[8];
#pragma unroll
  for (int e=0;e<8;e++) h[e]=0;
  const int base = t*64;
  for (int i=0;i<64;i++) h[gate_idx[base+i]]++;
#pragma unroll
  for (int e=0;e<8;e++) hist[t][e]=h[e];
  {
    const int e = t & 7, c = t >> 3;
    float s = 0.f;
    for (int r=c; r<4096; r+=32) s += partial_imp[(size_t)r*8+e];
    impbuf[c][e] = s;
  }
  __syncthreads();
  if (t < 8){
    int run = 0;
    for (int i=0;i<256;i++){ int v = hist[i][t]; hist[i][t] = run; run += v; }
    cnt[t] = run < CAP ? run : CAP;
  }
  __syncthreads();
#pragma unroll
  for (int e=0;e<8;e++) h[e]=hist[t][e];
  for (int i=0;i<64;i++){
    const int n = base+i;
    const int e = gate_idx[n];
    const int p = h[e]++;
    if (p < CAP){ const int s = e*CAP+p; slot_or_neg[n]=s; tok_of_slot[s]=n; }
    else slot_or_neg[n] = -1;
  }
  if (t==0){
    float imp[8]; float m = 0.f;
    for (int e=0;e<8;e++){ float s=0.f; for (int c=0;c<32;c++) s+=impbuf[c][e]; imp[e]=s; m+=s; }
    m *= 0.125f;
    float var = 0.f;
    for (int e=0;e<8;e++){ const float d=imp[e]-m; var += d*d; }
    var *= 0.125f;
    out_losses[0] = 1.0f;
    out_losses[1] = var/(m*m);
  }
}

// ---------------------------------------------------------------------------
// Weight transpose + fp32->bf16, both W1 and W2 in one launch.
// W [E][K][N] -> Wt [E][N][K] (k-contiguous rows for the MFMA B-operand).
// ---------------------------------------------------------------------------
__global__ __launch_bounds__(256) void cvt_w_t(
    const float* __restrict__ W1, const float* __restrict__ W2,
    unsigned short* __restrict__ W1t, unsigned short* __restrict__ W2t)
{
  __shared__ float t[64][65];
  const bool second = blockIdx.z >= 8;
  const int e = second ? (int)blockIdx.z - 8 : (int)blockIdx.z;
  const float* W = second ? W2 : W1;
  unsigned short* Wt = second ? W2t : W1t;
  const int K = second ? HDIM : DDIM;
  const int N = second ? DDIM : HDIM;
  const int nt = second ? (int)blockIdx.y : (int)blockIdx.x;
  const int kt = second ? (int)blockIdx.x : (int)blockIdx.y;
  const int n0 = nt*64, k0 = kt*64;

  const int lr = threadIdx.x >> 4;          // 0..15
  const int lc = (threadIdx.x & 15) * 4;    // 0..60
#pragma unroll
  for (int i=0;i<4;i++){
    const int r = i*16 + lr;
    const float4 v = *(const float4*)(W + ((size_t)e*K + k0 + r)*N + n0 + lc);
    t[r][lc+0]=v.x; t[r][lc+1]=v.y; t[r][lc+2]=v.z; t[r][lc+3]=v.w;
  }
  __syncthreads();
  const int sr = threadIdx.x >> 3;          // 0..31 (n-row within half)
  const int sc = (threadIdx.x & 7) * 8;     // 0..56 (k offset)
#pragma unroll
  for (int i=0;i<2;i++){
    const int r = i*32 + sr;
    u16x8 o;
#pragma unroll
    for (int j=0;j<8;j++) o[j] = f2bf(t[sc+j][r]);
    *(u16x8*)(Wt + ((size_t)e*N + n0 + r)*K + k0 + sc) = o;
  }
}

// ---------------------------------------------------------------------------
// 8-phase 256x256 grouped FFN GEMM (T3+T4+T5 stack, plain-HIP port of the
// m201/m248 template). BK=64 staged as two 32-k halves; 8 waves (2M x 4N),
// per-wave 128x64 output = acc[8][4] of 16x16x32 bf16 MFMA fragments.
//
// LDS: per operand a ring of 4 half-slots (16 KB each): slot(t,kh)=(2t+kh)&3.
// Consecutive tiles use disjoint slot pairs; an overwrite is always >=2
// barriers after the slot's last ds_read.
// Half-slot layout: [256 rows][32 k] bf16, 16B chunks XOR-swizzled
// chunk' = chunk ^ ((row>>1)&3)  (2-way-max bank aliasing = free).
// global_load_lds writes linearly, so the READ swizzle is pre-applied to the
// per-lane GLOBAL source k-chunk (same involution) — rule 21 both-sides.
//
// Per K-tile: 4 phases: {ds_read subtile | issue 1 half-tile prefetch ->
// counted vmcnt(4) at phases 1,3 -> s_barrier -> lgkmcnt(0) -> setprio(1),
// 16 MFMA, setprio(0) -> s_barrier}. vmcnt induction: <=8 loads in flight,
// wait-to-4 retires exactly the half-tiles read 2 phases later; never 0 in
// the main loop (last tile drains with one vmcnt(0)).
// ---------------------------------------------------------------------------
template<int PHASE>
__global__ __launch_bounds__(512,2) void ffn_mfma(
    const unsigned short* __restrict__ A,   // PHASE1: xbf [NTOK][1024]; PHASE2: hbf [ECAP][4096]
    const unsigned short* __restrict__ Bt,  // [E][NN][K] k-contiguous
    const float* __restrict__ bias,         // [E][NN]
    const int* __restrict__ tok_of_slot,
    const int* __restrict__ cnt,
    const float* __restrict__ gate_value,
    void* __restrict__ Out)
{
  constexpr int K  = (PHASE==1)? DDIM : HDIM;
  constexpr int NN = (PHASE==1)? HDIM : DDIM;
  constexpr int NT = K/64;                  // K-tiles: 16 or 64 (even)

  const int rowtile = blockIdx.y;           // 0..95
  const int coltile = blockIdx.x;           // 0..NN/256-1
  const int e  = rowtile / RT256_PER_E;
  const int r0 = (rowtile - e*RT256_PER_E)*256;
  const int ce = cnt[e];
  if (r0 >= ce) return;                     // block-uniform early exit

  __shared__ alignas(16) char smem[131072]; // A: 4x16KB @0, B: 4x16KB @65536

  const int tid = threadIdx.x;
  const int l   = tid & 63;
  const int w   = __builtin_amdgcn_readfirstlane(tid >> 6);  // 0..7

  // ---- staging: per call c (0/1): tile row = c*128 + w*16 + (l>>2)
  const int srow0 = w*16 + (l>>2);
  const int srow1 = 128 + srow0;
  const int schunk = ((l&3) ^ ((l>>3)&3)) * 8;   // pre-swizzled src k-chunk (elems)

  const unsigned short *agp0, *agp1;
  if (PHASE==1){
    const int t0 = (r0 + srow0 < ce) ? tok_of_slot[rowtile*256 + srow0] : 0;
    const int t1 = (r0 + srow1 < ce) ? tok_of_slot[rowtile*256 + srow1] : 0;
    agp0 = A + (size_t)t0*K + schunk;
    agp1 = A + (size_t)t1*K + schunk;
  } else {
    agp0 = A + (size_t)(rowtile*256 + srow0)*K + schunk;
    agp1 = A + (size_t)(rowtile*256 + srow1)*K + schunk;
  }
  const unsigned short* bgp0 = Bt + ((size_t)e*NN + coltile*256 + srow0)*K + schunk;
  const unsigned short* bgp1 = Bt + ((size_t)e*NN + coltile*256 + srow1)*K + schunk;

#define STAGE_A(S, KE) { char* d_ = smem + (S)*16384 + w*1024;          \
    gl16(agp0 + (KE), d_); gl16(agp1 + (KE), d_ + 8192); }
#define STAGE_B(S, KE) { char* d_ = smem + 65536 + (S)*16384 + w*1024;  \
    gl16(bgp0 + (KE), d_); gl16(bgp1 + (KE), d_ + 8192); }

  // ---- fragment read offsets (bytes within a half-slot)
  const int wm = w >> 2, wn = w & 3;        // 2M x 4N wave grid
  const int lm = l & 15;
  const int kg = l >> 4;                    // 0..3 (8-elem chunk within 32-k half)
  const int swz = ((kg ^ ((lm>>1)&3)) * 16);
  int aoff[8], boff[4];
#pragma unroll
  for (int i=0;i<8;i++) aoff[i] = (wm*128 + i*16 + lm)*64 + swz;
#pragma unroll
  for (int i=0;i<4;i++) boff[i] = (wn*64 + i*16 + lm)*64 + swz;

#define LDA(S, MI) (*(const bf16x8*)(smem + (S)*16384 + aoff[MI]))
#define LDB(S, NI) (*(const bf16x8*)(smem + 65536 + (S)*16384 + boff[NI]))

  f32x4 acc[8][4];
#pragma unroll
  for (int i=0;i<8;i++)
#pragma unroll
    for (int j=0;j<4;j++) acc[i][j] = (f32x4){0.f,0.f,0.f,0.f};

#define MFMA_ROW(MI, AF) {                                                      \
    acc[MI][0] = __builtin_amdgcn_mfma_f32_16x16x32_bf16(AF, bfr0, acc[MI][0],0,0,0); \
    acc[MI][1] = __builtin_amdgcn_mfma_f32_16x16x32_bf16(AF, bfr1, acc[MI][1],0,0,0); \
    acc[MI][2] = __builtin_amdgcn_mfma_f32_16x16x32_bf16(AF, bfr2, acc[MI][2],0,0,0); \
    acc[MI][3] = __builtin_amdgcn_mfma_f32_16x16x32_bf16(AF, bfr3, acc[MI][3],0,0,0); }

  bf16x8 bfr0, bfr1, bfr2, bfr3;

#define DO_TILE(T, S0, S1, NS0, NS1) {                                          \
    const int t_ = (T);                                                         \
    const bool pf_ = (t_ + 1 < NT);                                             \
    const int kn_ = (t_ + 1)*64;                                                \
    /* ---- p0: A(s0) m0-3 + B(s0); issue A(t+1,k0) */                          \
    bf16x8 af0 = LDA(S0,0), af1 = LDA(S0,1), af2 = LDA(S0,2), af3 = LDA(S0,3);  \
    bfr0 = LDB(S0,0); bfr1 = LDB(S0,1); bfr2 = LDB(S0,2); bfr3 = LDB(S0,3);     \
    if (pf_) STAGE_A(NS0, kn_);                                                 \
    __builtin_amdgcn_s_barrier();                                               \
    asm volatile("s_waitcnt lgkmcnt(0)" ::: "memory");                          \
    __builtin_amdgcn_s_setprio(1);                                              \
    MFMA_ROW(0, af0); MFMA_ROW(1, af1); MFMA_ROW(2, af2); MFMA_ROW(3, af3);     \
    __builtin_amdgcn_s_setprio(0);                                              \
    __builtin_amdgcn_s_barrier();                                               \
    /* ---- p1: A(s0) m4-7; issue B(t+1,k0); wait for (t,k1) */                 \
    af0 = LDA(S0,4); af1 = LDA(S0,5); af2 = LDA(S0,6); af3 = LDA(S0,7);         \
    if (pf_){ STAGE_B(NS0, kn_);                                                \
              asm volatile("s_waitcnt vmcnt(4)" ::: "memory"); }                \
    else      asm volatile("s_waitcnt vmcnt(0)" ::: "memory");                  \
    __builtin_amdgcn_s_barrier();                                               \
    asm volatile("s_waitcnt lgkmcnt(0)" ::: "memory");                          \
    __builtin_amdgcn_s_setprio(1);                                              \
    MFMA_ROW(4, af0); MFMA_ROW(5, af1); MFMA_ROW(6, af2); MFMA_ROW(7, af3);     \
    __builtin_amdgcn_s_setprio(0);                                              \
    __builtin_amdgcn_s_barrier();                                               \
    /* ---- p2: A(s1) m0-3 + B(s1); issue A(t+1,k1) */                          \
    af0 = LDA(S1,0); af1 = LDA(S1,1); af2 = LDA(S1,2); af3 = LDA(S1,3);         \
    bfr0 = LDB(S1,0); bfr1 = LDB(S1,1); bfr2 = LDB(S1,2); bfr3 = LDB(S1,3);     \
    if (pf_) STAGE_A(NS1, kn_ + 32);                                            \
    __builtin_amdgcn_s_barrier();                                               \
    asm volatile("s_waitcnt lgkmcnt(0)" ::: "memory");                          \
    __builtin_amdgcn_s_setprio(1);                                              \
    MFMA_ROW(0, af0); MFMA_ROW(1, af1); MFMA_ROW(2, af2); MFMA_ROW(3, af3);     \
    __builtin_amdgcn_s_setprio(0);                                              \
    __builtin_amdgcn_s_barrier();                                               \
    /* ---- p3: A(s1) m4-7; issue B(t+1,k1); wait for (t+1,k0) */               \
    af0 = LDA(S1,4); af1 = LDA(S1,5); af2 = LDA(S1,6); af3 = LDA(S1,7);         \
    if (pf_){ STAGE_B(NS1, kn_ + 32);                                           \
              asm volatile("s_waitcnt vmcnt(4)" ::: "memory"); }                \
    __builtin_amdgcn_s_barrier();                                               \
    asm volatile("s_waitcnt lgkmcnt(0)" ::: "memory");                          \
    __builtin_amdgcn_s_setprio(1);                                              \
    MFMA_ROW(4, af0); MFMA_ROW(5, af1); MFMA_ROW(6, af2); MFMA_ROW(7, af3);     \
    __builtin_amdgcn_s_setprio(0);                                              \
    __builtin_amdgcn_s_barrier(); }

  // ---- prologue: stage tile 0 fully (8 loads), wait k0-pair, sync
  STAGE_A(0, 0); STAGE_B(0, 0); STAGE_A(1, 32); STAGE_B(1, 32);
  asm volatile("s_waitcnt vmcnt(4)" ::: "memory");
  __builtin_amdgcn_s_barrier();

  for (int tp = 0; tp < NT; tp += 2){
    DO_TILE(tp,   0, 1, 2, 3);
    DO_TILE(tp+1, 2, 3, 0, 1);
  }

  // ---- epilogue. C/D layout: col = lane&15, row = (lane>>4)*4 + reg
  const float* bp = bias + (size_t)e*NN + coltile*256 + wn*64;
  float bv[4];
#pragma unroll
  for (int ni=0;ni<4;ni++) bv[ni] = bp[ni*16 + lm];

  if (PHASE==1){
    unsigned short* hb = (unsigned short*)Out;
#pragma unroll
    for (int mi=0;mi<8;mi++){
#pragma unroll
      for (int r=0;r<4;r++){
        const int row = wm*128 + mi*16 + kg*4 + r;
        unsigned short* hr = hb + (size_t)(rowtile*256 + row)*NN + coltile*256 + wn*64;
#pragma unroll
        for (int ni=0;ni<4;ni++){
          const float v = acc[mi][ni][r] + bv[ni];
          hr[ni*16 + lm] = f2bf(siluf(v));
        }
      }
    }
  } else {
    float* op = (float*)Out;
#pragma unroll
    for (int mi=0;mi<8;mi++){
#pragma unroll
      for (int r=0;r<4;r++){
        const int row = wm*128 + mi*16 + kg*4 + r;
        if (r0 + row < ce){
          const int tok = tok_of_slot[rowtile*256 + row];
          const float g = gate_value[tok];
          float* orow = op + (size_t)tok*NN + coltile*256 + wn*64;
#pragma unroll
          for (int ni=0;ni<4;ni++)
            orow[ni*16 + lm] = (acc[mi][ni][r] + bv[ni])*g;
        }
      }
    }
  }
#undef STAGE_A
#undef STAGE_B
#undef LDA
#undef LDB
#undef MFMA_ROW
#undef DO_TILE
}

// ---------------------------------------------------------------------------
// Dropped tokens pass through: out[n] = x[n] * gate[n]. One wave per token.
// ---------------------------------------------------------------------------
__global__ __launch_bounds__(256) void passthrough_kernel(
    const float* __restrict__ x, const int* __restrict__ slot_or_neg,
    const float* __restrict__ gate_value, float* __restrict__ out)
{
  const int wave = threadIdx.x >> 6;
  const int lane = threadIdx.x & 63;
  const int n = blockIdx.x*4 + wave;
  if (slot_or_neg[n] >= 0) return;
  const float g = gate_value[n];
#pragma unroll
  for (int k=0;k<4;k++){
    const int d = (k*64 + lane)*4;
    float4 v = *(const float4*)(x + (size_t)n*DDIM + d);
    v.x*=g; v.y*=g; v.z*=g; v.w*=g;
    *(float4*)(out + (size_t)n*DDIM + d) = v;
  }
}

extern "C" void kernel_launch(void* const* d_in, const int* in_sizes, int n_in,
                              void* d_out, int out_size, void* d_ws, size_t ws_size,
                              hipStream_t stream)
{
  const float* x  = (const float*)d_in[0];
  const float* Wr = (const float*)d_in[1];
  const float* br = (const float*)d_in[2];
  const float* W1 = (const float*)d_in[3];
  const float* b1 = (const float*)d_in[4];
  const float* W2 = (const float*)d_in[5];
  const float* b2 = (const float*)d_in[6];
  float* out = (float*)d_out;

  char* ws = (char*)d_ws;
  float*          gate_value  = (float*)(ws + OFF_GATE);
  int*            gate_idx    = (int*)  (ws + OFF_GIDX);
  int*            slot_or_neg = (int*)  (ws + OFF_SLOT);
  int*            tok_of_slot = (int*)  (ws + OFF_TOS);
  int*            cnt         = (int*)  (ws + OFF_CNT);
  float*          partial_imp = (float*)(ws + OFF_PIMP);
  unsigned short* xbf         = (unsigned short*)(ws + OFF_XBF);
  unsigned short* W1t         = (unsigned short*)(ws + OFF_W1T);
  unsigned short* W2t         = (unsigned short*)(ws + OFF_W2T);
  unsigned short* hbf         = (unsigned short*)(ws + OFF_HB);

  // weight transpose+convert (independent of router/scan), single launch
  cvt_w_t<<<dim3(64, 16, 16), 256, 0, stream>>>(W1, W2, W1t, W2t);

  router_kernel<<<NTOK/4, 256, 0, stream>>>(x, Wr, br, gate_value, gate_idx,
                                            partial_imp, xbf);
  scan_kernel<<<1, 256, 0, stream>>>(gate_idx, partial_imp, slot_or_neg, tok_of_slot,
                                     cnt, out + (size_t)NTOK*DDIM);

  ffn_mfma<1><<<dim3(HDIM/256, ECAP/256), 512, 0, stream>>>(
      xbf, W1t, b1, tok_of_slot, cnt, gate_value, (void*)hbf);
  ffn_mfma<2><<<dim3(DDIM/256, ECAP/256), 512, 0, stream>>>(
      hbf, W2t, b2, tok_of_slot, cnt, gate_value, (void*)out);

  passthrough_kernel<<<NTOK/4, 256, 0, stream>>>(x, slot_or_neg, gate_value, out);
}